// Round 3
// baseline (208.403 us; speedup 1.0000x reference)
//
#include <hip/hip_runtime.h>

#define LAMBDA_COORD 5.0f
#define LAMBDA_NOOBJ 0.5f
#define WH_EPS 1e-6f
#define IOU_EPS 1e-6f

constexpr int CELLS   = 128;             // cells per chunk
constexpr int CFLOATS = CELLS * 30;      // 3840 floats per array per chunk
constexpr int CVEC4   = CFLOATS / 4;     // 960 float4 per array per chunk
constexpr int GRID    = 1280;            // 5 blocks/CU * 256 CUs

// IOU between box a (cx,cy,w,h) and b, matching _iou_yolo exactly.
__device__ __forceinline__ float iou_yolo(float a0, float a1, float a2, float a3,
                                          float b0, float b1, float b2, float b3) {
    float ax1 = a0 - a2 * 0.5f, ay1 = a1 - a3 * 0.5f;
    float ax2 = a0 + a2 * 0.5f, ay2 = a1 + a3 * 0.5f;
    float bx1 = b0 - b2 * 0.5f, by1 = b1 - b3 * 0.5f;
    float bx2 = b0 + b2 * 0.5f, by2 = b1 + b3 * 0.5f;
    float iw = fmaxf(fminf(ax2, bx2) - fmaxf(ax1, bx1), 0.0f);
    float ih = fmaxf(fminf(ay2, by2) - fmaxf(ay1, by1), 0.0f);
    float inter = iw * ih;
    float area_a = fabsf((ax2 - ax1) * (ay2 - ay1));
    float area_b = fabsf((bx2 - bx1) * (by2 - by1));
    return inter / (area_a + area_b - inter + IOU_EPS);
}

// Everything except the 20-class SSE (that part is computed by waves 2-3).
__device__ __forceinline__ float cell_main(const float* t, const float* p) {
    const float b0 = t[0], b1 = t[1], b2 = t[2], b3 = t[3], t4 = t[4];

    float iou1 = iou_yolo(b0, b1, b2, b3, p[0], p[1], p[2], p[3]);
    float iou2 = iou_yolo(b0, b1, b2, b3, p[5], p[6], p[7], p[8]);
    bool use1 = iou1 > iou2;

    float bh0 = use1 ? p[0] : p[5];
    float bh1 = use1 ? p[1] : p[6];
    float bh2 = use1 ? p[2] : p[7];
    float bh3 = use1 ? p[3] : p[8];
    float conf_c = use1 ? p[4] : p[9];
    float conf_o = use1 ? p[9] : p[4];

    float dx = b0 - bh0, dy = b1 - bh1;
    float xy = LAMBDA_COORD * (dx * dx + dy * dy);

    float sw = sqrtf(b2) - sqrtf(fabsf(bh2 + WH_EPS));
    float sh = sqrtf(b3) - sqrtf(fabsf(bh3 + WH_EPS));
    float wh = LAMBDA_COORD * (sw * sw + sh * sh);

    float dc = t4 - conf_c;
    float obj_conf = dc * dc;
    float noobj_in_obj = LAMBDA_NOOBJ * conf_o * conf_o;

    float obj_terms = xy + wh + obj_conf + noobj_in_obj;  // cls added by partner wave

    float d4 = t4 - p[4], d9 = t4 - p[9];
    float noobj_terms = LAMBDA_NOOBJ * (d4 * d4 + d9 * d9);

    return (t4 == 1.0f) ? obj_terms : noobj_terms;
}

// Fire-and-forget 16B global->LDS: wave-uniform LDS base, per-lane global addr.
__device__ __forceinline__ void stage16(const float4* g_wave, float4* l_wave, int lane) {
    __builtin_amdgcn_global_load_lds(
        (const __attribute__((address_space(1))) void*)(g_wave + lane),
        (__attribute__((address_space(3))) void*)l_wave,
        16, 0, 0);
}

__global__ __launch_bounds__(256) void yolo_loss_kernel(
    const float* __restrict__ t_g, const float* __restrict__ p_g,
    float* __restrict__ out, int nchunks, float inv_batch) {
    __shared__ float4 st4[CVEC4];
    __shared__ float4 sp4[CVEC4];
    __shared__ float swave[4];
    float* st = (float*)st4;
    float* sp = (float*)sp4;

    const int tid  = threadIdx.x;
    const int lane = tid & 63;
    const int wb   = tid - lane;          // wave base within block (0,64,128,192)

    float v = 0.0f;

    for (int chunk = blockIdx.x; chunk < nchunks; chunk += GRID) {
        const float4* tg = (const float4*)t_g + (size_t)chunk * CVEC4;
        const float4* pg = (const float4*)p_g + (size_t)chunk * CVEC4;

        // Stage 2 x 960 float4 = 30,720 B; every load issued before any wait.
#pragma unroll
        for (int j = 0; j < 3; ++j) {
            int b = wb + j * 256;
            stage16(tg + b, st4 + b, lane);
            stage16(pg + b, sp4 + b, lane);
        }
        if (tid < 192) {                  // waves 0..2, remaining 192 float4 each
            int b = wb + 768;
            stage16(tg + b, st4 + b, lane);
            stage16(pg + b, sp4 + b, lane);
        }
        __syncthreads();                  // vmcnt(0) drain + barrier

        // Compute: waves 0-1 -> box/conf/noobj for cell tid;
        //          waves 2-3 -> class SSE for cell tid-128 (obj cells only).
        if (tid < CELLS) {
            v += cell_main(st + tid * 30, sp + tid * 30);
        } else {
            const int c = tid - CELLS;
            const float* t = st + c * 30;
            const float* p = sp + c * 30;
            if (t[4] == 1.0f) {
                float cls = 0.0f;
#pragma unroll
                for (int k = 10; k < 30; ++k) {
                    float d = t[k] - p[k];
                    cls += d * d;
                }
                v += cls;
            }
        }
        __syncthreads();                  // LDS reuse next iteration
    }

    // wave64 reduction -> per-wave LDS -> one atomic per block
#pragma unroll
    for (int off = 32; off > 0; off >>= 1)
        v += __shfl_down(v, off, 64);

    const int wid = tid >> 6;
    if (lane == 0) swave[wid] = v;
    __syncthreads();
    if (tid == 0) {
        float s = swave[0] + swave[1] + swave[2] + swave[3];
        atomicAdd(out, s * inv_batch);
    }
}

extern "C" void kernel_launch(void* const* d_in, const int* in_sizes, int n_in,
                              void* d_out, int out_size, void* d_ws, size_t ws_size,
                              hipStream_t stream) {
    const float* t = (const float*)d_in[0];  // y_trues
    const float* p = (const float*)d_in[1];  // y_preds
    float* out = (float*)d_out;

    const int total  = in_sizes[0];          // 24,084,480
    const int cells  = total / 30;           // 802,816
    const int chunks = cells / CELLS;        // 6,272 (exact)
    const int batch  = cells / 49;           // 16,384
    const float inv_batch = 1.0f / (float)batch;

    // d_out is poisoned (0xAA) before every replay — zero it on-stream.
    hipMemsetAsync(out, 0, sizeof(float), stream);

    yolo_loss_kernel<<<GRID, 256, 0, stream>>>(t, p, out, chunks, inv_batch);
}